// Round 1
// baseline (680.556 us; speedup 1.0000x reference)
//
#include <hip/hip_runtime.h>
#include <math.h>

// Heatmap: out[b,j,r,c] = exp(-((r - ceil(y))^2 + (c - ceil(x))^2) / 3)
// H = W = 64, N_JOINTS = 21, B = 2048. Output f32, 672 MiB -> write-BW bound.
//
// Separable: exp2(k*dr^2) * exp2(k*dc^2), k = -log2(e)/3.
// One 256-thread block per (batch*joint). Thread t owns cols (t%16)*4..+3
// (constant across its 4 row-iterations) and rows j*16 + t/16.
// Per j, lanes 0..63 of a wave store contiguous float4 -> 1024B coalesced.

__global__ __launch_bounds__(256) void heatmap_kernel(
    const float* __restrict__ x, float* __restrict__ out) {
    const int bj = blockIdx.x;   // flattened (batch, joint)
    const int t  = threadIdx.x;  // 0..255

    const float px = ceilf(x[bj * 2 + 0]);  // col center
    const float py = ceilf(x[bj * 2 + 1]);  // row center

    constexpr float k = -0.48089834696298783f;  // -(1/3) * log2(e)

    // Column factors: constant across the 4 row iterations.
    const int c0 = (t & 15) * 4;
    const float d0 = (float)(c0 + 0) - px;
    const float d1 = (float)(c0 + 1) - px;
    const float d2 = (float)(c0 + 2) - px;
    const float d3 = (float)(c0 + 3) - px;
    const float cfx = exp2f(d0 * d0 * k);
    const float cfy = exp2f(d1 * d1 * k);
    const float cfz = exp2f(d2 * d2 * k);
    const float cfw = exp2f(d3 * d3 * k);

    float4* __restrict__ outv = (float4*)(out + (size_t)bj * 4096);
    const int baseRow = t >> 4;  // 0..15

#pragma unroll
    for (int j = 0; j < 4; ++j) {
        const float dr = (float)(j * 16 + baseRow) - py;
        const float rf = exp2f(dr * dr * k);
        float4 v;
        v.x = rf * cfx;
        v.y = rf * cfy;
        v.z = rf * cfz;
        v.w = rf * cfw;
        outv[j * 256 + t] = v;
    }
}

extern "C" void kernel_launch(void* const* d_in, const int* in_sizes, int n_in,
                              void* d_out, int out_size, void* d_ws, size_t ws_size,
                              hipStream_t stream) {
    const float* x = (const float*)d_in[0];
    float* out = (float*)d_out;
    const int nbj = in_sizes[0] / 2;  // 2048 * 21 = 43008
    heatmap_kernel<<<nbj, 256, 0, stream>>>(x, out);
}

// Round 3
// 677.239 us; speedup vs baseline: 1.0049x; 1.0049x over previous
//
#include <hip/hip_runtime.h>
#include <math.h>

// Heatmap: out[b,j,r,c] = exp(-((r - ceil(y))^2 + (c - ceil(x))^2) / 3)
// H = W = 64, N_JOINTS = 21, B = 2048. Output f32 = 672 MiB -> write-BW bound.
//
// Separable: exp2(k*dr^2) * exp2(k*dc^2), k = -log2(e)/3.
// Persistent blocks: grid = 2048 (8 blocks/CU, full occupancy), each block
// streams 21 maps. Thread t owns cols (t%16)*4..+3 and rows t/16 + 16j.
// Per map: 8 exp2 + 4 nontemporal float4 stores per thread (1 KB/wave/instr,
// fully coalesced). Next map's (x,y) prefetched before current map's stores.

typedef float f32x4 __attribute__((ext_vector_type(4)));  // clang vector:
// __builtin_nontemporal_store rejects HIP_vector_type<float,4>.

__global__ __launch_bounds__(256) void heatmap_kernel(
    const float* __restrict__ x, float* __restrict__ out, int nbj) {
    const int t  = threadIdx.x;              // 0..255
    const int c0 = (t & 15) * 4;             // column group
    const int r0 = t >> 4;                   // base row 0..15

    constexpr float k = -0.48089834696298783f;  // -(1/3) * log2(e)

    const float2* __restrict__ xx = (const float2*)x;

    int bj = blockIdx.x;
    if (bj >= nbj) return;
    float2 p = xx[bj];

    while (true) {
        const int bj_next = bj + gridDim.x;
        const bool has_next = bj_next < nbj;
        float2 pn = p;
        if (has_next) pn = xx[bj_next];      // prefetch next map's keypoint

        const float px = ceilf(p.x);
        const float py = ceilf(p.y);

        // Column factors (4 per thread)
        const float d0 = (float)(c0 + 0) - px;
        const float d1 = (float)(c0 + 1) - px;
        const float d2 = (float)(c0 + 2) - px;
        const float d3 = (float)(c0 + 3) - px;
        const float cfx = exp2f(d0 * d0 * k);
        const float cfy = exp2f(d1 * d1 * k);
        const float cfz = exp2f(d2 * d2 * k);
        const float cfw = exp2f(d3 * d3 * k);

        f32x4* __restrict__ outv = (f32x4*)(out + (size_t)bj * 4096);

#pragma unroll
        for (int j = 0; j < 4; ++j) {
            const float dr = (float)(j * 16 + r0) - py;
            const float rf = exp2f(dr * dr * k);
            f32x4 v;
            v.x = rf * cfx;
            v.y = rf * cfy;
            v.z = rf * cfz;
            v.w = rf * cfw;
            __builtin_nontemporal_store(v, &outv[j * 256 + t]);
        }

        if (!has_next) break;
        bj = bj_next;
        p = pn;
    }
}

extern "C" void kernel_launch(void* const* d_in, const int* in_sizes, int n_in,
                              void* d_out, int out_size, void* d_ws, size_t ws_size,
                              hipStream_t stream) {
    const float* x = (const float*)d_in[0];
    float* out = (float*)d_out;
    const int nbj = in_sizes[0] / 2;  // 2048 * 21 = 43008
    const int grid = nbj < 2048 ? nbj : 2048;  // 8 blocks/CU, 21 maps/block
    heatmap_kernel<<<grid, 256, 0, stream>>>(x, out, nbj);
}